// Round 1
// baseline (477.275 us; speedup 1.0000x reference)
//
#include <hip/hip_runtime.h>
#include <hip/hip_bf16.h>
#include <stdint.h>

// Problem constants (fixed by setup_inputs)
#define B_SZ  8
#define N_Q   8192
#define M_PT  2048
#define C1    128
#define C2    256
#define CIN   384      // C1 + C2
#define H_OUT 256
#define R_TOT 65536    // B_SZ * N_Q

typedef __bf16 bf16x8 __attribute__((ext_vector_type(8)));
typedef __bf16 bf16x4 __attribute__((ext_vector_type(4)));
typedef __bf16 bf16x2 __attribute__((ext_vector_type(2)));
typedef float  f32x4  __attribute__((ext_vector_type(4)));

// Async global->LDS, 16B per lane. LDS dest is wave-uniform base + lane*16.
__device__ __forceinline__ void async_copy16(const void* g, void* l) {
    __builtin_amdgcn_global_load_lds(
        (const __attribute__((address_space(1))) unsigned int*)g,
        (__attribute__((address_space(3))) unsigned int*)l,
        16, 0, 0);
}

// ---------------------------------------------------------------------------
// fp32 -> bf16 convert (weights)
// ---------------------------------------------------------------------------
__global__ __launch_bounds__(256) void f2bf(const float* __restrict__ in,
                                            __bf16* __restrict__ o, int n) {
    int i = blockIdx.x * 256 + threadIdx.x;
    if (i < n) o[i] = (__bf16)in[i];
}

// ---------------------------------------------------------------------------
// 3-NN inverse-distance interpolation + concat -> xb (bf16, [R_TOT x CIN])
// grid: B_SZ*32 blocks of 256 threads; each block: 256 query points, one batch
// ---------------------------------------------------------------------------
__global__ __launch_bounds__(256) void interp_concat(
    const float* __restrict__ xyz1, const float* __restrict__ xyz2,
    const float* __restrict__ p1,   const float* __restrict__ p2,
    __bf16* __restrict__ xb) {
    __shared__ float4 pos[M_PT];        // (x,y,z,|p|^2) 32 KB
    __shared__ float  wgt[256 * 3];
    __shared__ int    ids[256 * 3];

    const int tid = threadIdx.x;
    const int b   = blockIdx.x >> 5;        // 32 blocks per batch
    const int q0  = (blockIdx.x & 31) << 8;

    // stage xyz2[b] with precomputed squared norms
    const float* x2 = xyz2 + (size_t)b * M_PT * 3;
    for (int j = tid; j < M_PT; j += 256) {
        float x = x2[j * 3], y = x2[j * 3 + 1], z = x2[j * 3 + 2];
        pos[j] = make_float4(x, y, z, x * x + y * y + z * z);
    }
    __syncthreads();

    // phase 1: thread-per-query top-3 (reference's |a|^2+|b|^2-2ab formula so
    // near-tie neighbor ordering matches jax top_k; strict < keeps lower idx)
    {
        const float* q1 = xyz1 + (size_t)(b * N_Q + q0 + tid) * 3;
        float x1 = q1[0], y1 = q1[1], z1 = q1[2];
        float n1 = x1 * x1 + y1 * y1 + z1 * z1;
        float d0 = 3.4e38f, d1 = 3.4e38f, d2 = 3.4e38f;
        int   i0 = 0, i1 = 0, i2 = 0;
        for (int j = 0; j < M_PT; ++j) {
            float4 p  = pos[j];
            float dot = fmaf(x1, p.x, fmaf(y1, p.y, z1 * p.z));
            float d   = fmaf(-2.f, dot, n1 + p.w);
            if (d < d2) {
                if (d < d1) {
                    d2 = d1; i2 = i1;
                    if (d < d0) { d1 = d0; i1 = i0; d0 = d; i0 = j; }
                    else        { d1 = d;  i1 = j; }
                } else { d2 = d; i2 = j; }
            }
        }
        float r0 = 1.f / (d0 + 1e-8f), r1 = 1.f / (d1 + 1e-8f), r2 = 1.f / (d2 + 1e-8f);
        float rs = 1.f / (r0 + r1 + r2);
        wgt[tid * 3] = r0 * rs; wgt[tid * 3 + 1] = r1 * rs; wgt[tid * 3 + 2] = r2 * rs;
        ids[tid * 3] = i0;      ids[tid * 3 + 1] = i1;      ids[tid * 3 + 2] = i2;
    }
    __syncthreads();

    // phase 2: wave-per-query cooperative gather (coalesced 1KB row reads)
    const int wave = tid >> 6, lane = tid & 63;
    const float* p2b = p2 + (size_t)b * M_PT * C2;
    const float* p1b = p1 + (size_t)(b * N_Q + q0) * C1;
    __bf16* outp = xb + (size_t)(b * N_Q + q0) * CIN;
    for (int qq = wave; qq < 256; qq += 4) {
        float w0 = wgt[qq * 3], w1 = wgt[qq * 3 + 1], w2 = wgt[qq * 3 + 2];
        int   j0 = ids[qq * 3], j1 = ids[qq * 3 + 1], j2 = ids[qq * 3 + 2];
        const float4* ra = (const float4*)(p2b + (size_t)j0 * C2);
        const float4* rb = (const float4*)(p2b + (size_t)j1 * C2);
        const float4* rc = (const float4*)(p2b + (size_t)j2 * C2);
        float4 va = ra[lane], vb = rb[lane], vc = rc[lane];
        bf16x4 o;
        o[0] = (__bf16)(w0 * va.x + w1 * vb.x + w2 * vc.x);
        o[1] = (__bf16)(w0 * va.y + w1 * vb.y + w2 * vc.y);
        o[2] = (__bf16)(w0 * va.z + w1 * vb.z + w2 * vc.z);
        o[3] = (__bf16)(w0 * va.w + w1 * vb.w + w2 * vc.w);
        *(bf16x4*)(outp + (size_t)qq * CIN + C1 + lane * 4) = o;
        float2 pv = ((const float2*)(p1b + (size_t)qq * C1))[lane];
        bf16x2 o2; o2[0] = (__bf16)pv.x; o2[1] = (__bf16)pv.y;
        *(bf16x2*)(outp + (size_t)qq * CIN + lane * 2) = o2;
    }
}

// ---------------------------------------------------------------------------
// bf16 MFMA GEMM: C[r,o] = sum_k A[r,k]*Bw[o,k]   (both K-major, "NT")
// m97 structure: 128x128 tile, 4 waves each 64x64, BK=32, global_load_lds x16B
// grid: (R_TOT/128)*(H_OUT/128) = 1024 blocks of 256
// ---------------------------------------------------------------------------
template <int K, bool OUT_BF16>
__global__ __launch_bounds__(256, 2) void gemm_bt(const __bf16* __restrict__ A,
                                                  const __bf16* __restrict__ Bw,
                                                  void* __restrict__ Cout) {
    __shared__ __attribute__((aligned(16))) __bf16 As[128 * 32];
    __shared__ __attribute__((aligned(16))) __bf16 Bs[128 * 32];
    const int tid  = threadIdx.x;
    const int wave = tid >> 6, lane = tid & 63;
    const int wm = wave >> 1, wn = wave & 1;
    const int quad = lane >> 4, r16 = lane & 15;
    const int bx = blockIdx.x & 1, by = blockIdx.x >> 1;
    const int l4 = lane >> 2, lk = (lane & 3) * 8;

    f32x4 acc[4][4] = {};

    // staging: wave w covers LDS rows 32w..32w+31; row = 32w + 16i + lane/4,
    // k-chunk = (lane&3)*8  ->  LDS offset = w*2048 + i*1024 + lane*16 (exact)
    const __bf16* gA = A  + (size_t)(by * 128 + wave * 32 + l4) * K + lk;
    const __bf16* gB = Bw + (size_t)(bx * 128 + wave * 32 + l4) * K + lk;
    char* lA = (char*)As + wave * 2048;
    char* lB = (char*)Bs + wave * 2048;

    for (int k0 = 0; k0 < K; k0 += 32) {
        async_copy16(gA + k0,                 lA);
        async_copy16(gA + k0 + (size_t)16 * K, lA + 1024);
        async_copy16(gB + k0,                 lB);
        async_copy16(gB + k0 + (size_t)16 * K, lB + 1024);
        __syncthreads();   // compiler drains vmcnt before s_barrier

        bf16x8 af[4], bf[4];
#pragma unroll
        for (int t = 0; t < 4; ++t)
            af[t] = *(const bf16x8*)(As + (wm * 64 + t * 16 + r16) * 32 + quad * 8);
#pragma unroll
        for (int u = 0; u < 4; ++u)
            bf[u] = *(const bf16x8*)(Bs + (wn * 64 + u * 16 + r16) * 32 + quad * 8);
#pragma unroll
        for (int t = 0; t < 4; ++t)
#pragma unroll
            for (int u = 0; u < 4; ++u)
                acc[t][u] = __builtin_amdgcn_mfma_f32_16x16x32_bf16(af[t], bf[u], acc[t][u], 0, 0, 0);
        __syncthreads();   // protect LDS against next iteration's staging
    }

    // epilogue: C/D layout col=lane&15, row=(lane>>4)*4+reg [m89-verified]
#pragma unroll
    for (int t = 0; t < 4; ++t) {
#pragma unroll
        for (int u = 0; u < 4; ++u) {
            const int col = bx * 128 + wn * 64 + u * 16 + r16;
#pragma unroll
            for (int r = 0; r < 4; ++r) {
                const int row = by * 128 + wm * 64 + t * 16 + quad * 4 + r;
                if (OUT_BF16)
                    ((__bf16*)Cout)[(size_t)row * H_OUT + col] = (__bf16)acc[t][u][r];
                else
                    ((float*)Cout)[(size_t)row * H_OUT + col] = acc[t][u][r];
            }
        }
    }
}

// ---------------------------------------------------------------------------
// BatchNorm batch-stats, deterministic 2-stage (no atomics, no memset needed)
// stage1: 256 blocks x 256 rows -> partial sums; thread = channel
// ---------------------------------------------------------------------------
__global__ __launch_bounds__(256) void stats_bf16(const __bf16* __restrict__ y,
                                                  float* __restrict__ part) {
    const int c = threadIdx.x;
    const __bf16* p = y + (size_t)blockIdx.x * 256 * H_OUT + c;
    float s = 0.f, q = 0.f;
    for (int r = 0; r < 256; ++r) {
        float v = (float)p[(size_t)r * H_OUT];
        s += v; q = fmaf(v, v, q);
    }
    part[blockIdx.x * 512 + c]       = s;
    part[blockIdx.x * 512 + 256 + c] = q;
}

__global__ __launch_bounds__(256) void stats_f32(const float* __restrict__ y,
                                                 float* __restrict__ part) {
    const int c = threadIdx.x;
    const float* p = y + (size_t)blockIdx.x * 256 * H_OUT + c;
    float s = 0.f, q = 0.f;
    for (int r = 0; r < 256; ++r) {
        float v = p[(size_t)r * H_OUT];
        s += v; q = fmaf(v, v, q);
    }
    part[blockIdx.x * 512 + c]       = s;
    part[blockIdx.x * 512 + 256 + c] = q;
}

// stage2: fold partials -> per-channel scale/shift.  Bias b cancels in BN.
__global__ __launch_bounds__(256) void bn_finalize(const float* __restrict__ part,
                                                   const float* __restrict__ gamma,
                                                   const float* __restrict__ beta,
                                                   float* __restrict__ sc,
                                                   float* __restrict__ sh) {
    const int c = threadIdx.x;
    float s = 0.f, q = 0.f;
    for (int p = 0; p < 256; ++p) {
        s += part[p * 512 + c];
        q += part[p * 512 + 256 + c];
    }
    const float inv = 1.f / (float)R_TOT;
    float mean = s * inv;
    float var  = q * inv - mean * mean;
    float a    = gamma[c] * rsqrtf(var + 1e-5f);
    sc[c] = a;
    sh[c] = beta[c] - mean * a;
}

// ---------------------------------------------------------------------------
// apply BN+ReLU in place
// ---------------------------------------------------------------------------
__global__ __launch_bounds__(256) void apply_bf16(__bf16* __restrict__ y,
                                                  const float* __restrict__ sc,
                                                  const float* __restrict__ sh) {
    __shared__ float scs[256], shs[256];
    scs[threadIdx.x] = sc[threadIdx.x];
    shs[threadIdx.x] = sh[threadIdx.x];
    __syncthreads();
    size_t i = ((size_t)blockIdx.x * 256 + threadIdx.x) * 8;
    int c0 = (int)(i & 255);
    bf16x8 v = *(const bf16x8*)(y + i);
#pragma unroll
    for (int e = 0; e < 8; ++e) {
        float f = fmaf((float)v[e], scs[c0 + e], shs[c0 + e]);
        v[e] = (__bf16)fmaxf(f, 0.f);
    }
    *(bf16x8*)(y + i) = v;
}

__global__ __launch_bounds__(256) void apply_f32(float* __restrict__ y,
                                                 const float* __restrict__ sc,
                                                 const float* __restrict__ sh) {
    __shared__ float scs[256], shs[256];
    scs[threadIdx.x] = sc[threadIdx.x];
    shs[threadIdx.x] = sh[threadIdx.x];
    __syncthreads();
    size_t i = ((size_t)blockIdx.x * 256 + threadIdx.x) * 4;
    int c0 = (int)(i & 255);
    float4 v = *(const float4*)(y + i);
    v.x = fmaxf(fmaf(v.x, scs[c0 + 0], shs[c0 + 0]), 0.f);
    v.y = fmaxf(fmaf(v.y, scs[c0 + 1], shs[c0 + 1]), 0.f);
    v.z = fmaxf(fmaf(v.z, scs[c0 + 2], shs[c0 + 2]), 0.f);
    v.w = fmaxf(fmaf(v.w, scs[c0 + 3], shs[c0 + 3]), 0.f);
    *(float4*)(y + i) = v;
}

// ---------------------------------------------------------------------------
extern "C" void kernel_launch(void* const* d_in, const int* in_sizes, int n_in,
                              void* d_out, int out_size, void* d_ws, size_t ws_size,
                              hipStream_t stream) {
    const float* xyz1 = (const float*)d_in[0];
    const float* xyz2 = (const float*)d_in[1];
    const float* p1   = (const float*)d_in[2];
    const float* p2   = (const float*)d_in[3];
    const float* W1   = (const float*)d_in[4];
    // d_in[5] = b1  (cancels in batch-norm)
    const float* g1   = (const float*)d_in[6];
    const float* be1  = (const float*)d_in[7];
    const float* W2   = (const float*)d_in[8];
    // d_in[9] = b2  (cancels in batch-norm)
    const float* g2   = (const float*)d_in[10];
    const float* be2  = (const float*)d_in[11];
    float* out = (float*)d_out;

    // workspace layout (all offsets 16B-aligned); total ~84.7 MB
    char* ws = (char*)d_ws;
    __bf16* xb   = (__bf16*)(ws);                       // 65536*384*2 = 50331648
    __bf16* y1b  = (__bf16*)(ws + 50331648);            // 65536*256*2 = 33554432
    __bf16* wb1  = (__bf16*)(ws + 83886080);            // 256*384*2
    __bf16* wb2  = (__bf16*)(ws + 84082688);            // 256*256*2
    float*  part = (float*) (ws + 84213760);            // 256*512*4
    float*  sc1  = (float*) (ws + 84738048);
    float*  sh1  = sc1 + 256;
    float*  sc2  = sc1 + 512;
    float*  sh2  = sc1 + 768;

    f2bf<<<384, 256, 0, stream>>>(W1, wb1, H_OUT * CIN);
    f2bf<<<256, 256, 0, stream>>>(W2, wb2, H_OUT * H_OUT);

    interp_concat<<<B_SZ * 32, 256, 0, stream>>>(xyz1, xyz2, p1, p2, xb);

    gemm_bt<CIN, true><<<1024, 256, 0, stream>>>(xb, wb1, (void*)y1b);
    stats_bf16<<<256, 256, 0, stream>>>(y1b, part);
    bn_finalize<<<1, 256, 0, stream>>>(part, g1, be1, sc1, sh1);
    apply_bf16<<<8192, 256, 0, stream>>>(y1b, sc1, sh1);

    gemm_bt<H_OUT, false><<<1024, 256, 0, stream>>>(y1b, wb2, (void*)out);
    stats_f32<<<256, 256, 0, stream>>>(out, part);
    bn_finalize<<<1, 256, 0, stream>>>(part, g2, be2, sc2, sh2);
    apply_f32<<<16384, 256, 0, stream>>>(out, sc2, sh2);
}

// Round 2
// 330.493 us; speedup vs baseline: 1.4441x; 1.4441x over previous
//
#include <hip/hip_runtime.h>
#include <hip/hip_bf16.h>
#include <stdint.h>

// Problem constants (fixed by setup_inputs)
#define B_SZ  8
#define N_Q   8192
#define M_PT  2048
#define C1    128
#define C2    256
#define CIN   384      // C1 + C2
#define H_OUT 256
#define R_TOT 65536    // B_SZ * N_Q

#define NCH   8              // KNN chunks over M
#define CHM   (M_PT / NCH)   // 256 points per chunk
#define QPB   64             // queries per gather block

typedef __bf16 bf16x8 __attribute__((ext_vector_type(8)));
typedef __bf16 bf16x4 __attribute__((ext_vector_type(4)));
typedef __bf16 bf16x2 __attribute__((ext_vector_type(2)));
typedef float  f32x4  __attribute__((ext_vector_type(4)));

// Async global->LDS, 16B per lane. LDS dest is wave-uniform base + lane*16.
__device__ __forceinline__ void async_copy16(const void* g, void* l) {
    __builtin_amdgcn_global_load_lds(
        (const __attribute__((address_space(1))) unsigned int*)g,
        (__attribute__((address_space(3))) unsigned int*)l,
        16, 0, 0);
}

// ---------------------------------------------------------------------------
// fp32 -> bf16 convert (weights)
// ---------------------------------------------------------------------------
__global__ __launch_bounds__(256) void f2bf(const float* __restrict__ in,
                                            __bf16* __restrict__ o, int n) {
    int i = blockIdx.x * 256 + threadIdx.x;
    if (i < n) o[i] = (__bf16)in[i];
}

// ---------------------------------------------------------------------------
// KNN stage 1: per-chunk top-3.  grid = B*32*NCH = 2048 blocks of 256.
// block handles 256 queries vs one 256-point chunk of xyz2.
// 4 KB LDS -> 8 blocks/CU -> 100% occupancy (vs 1 block/CU before).
// ---------------------------------------------------------------------------
__global__ __launch_bounds__(256) void knn_partial(
    const float* __restrict__ xyz1, const float* __restrict__ xyz2,
    float* __restrict__ cand_d, int* __restrict__ cand_i) {
    __shared__ float4 pos[CHM];

    const int tid = threadIdx.x;
    const int c   = blockIdx.x & (NCH - 1);
    const int qb  = (blockIdx.x >> 3) & 31;
    const int b   = blockIdx.x >> 8;

    // stage this chunk of xyz2[b] with squared norms
    {
        const float* x2 = xyz2 + ((size_t)b * M_PT + c * CHM) * 3;
        float x = x2[tid * 3], y = x2[tid * 3 + 1], z = x2[tid * 3 + 2];
        pos[tid] = make_float4(x, y, z, x * x + y * y + z * z);
    }
    __syncthreads();

    const int q = b * N_Q + qb * 256 + tid;
    const float* q1 = xyz1 + (size_t)q * 3;
    float x1 = q1[0], y1 = q1[1], z1 = q1[2];
    float n1 = x1 * x1 + y1 * y1 + z1 * z1;
    float d0 = 3.4e38f, d1 = 3.4e38f, d2 = 3.4e38f;
    int   i0 = 0, i1 = 0, i2 = 0;
    const int jb = c * CHM;
#pragma unroll 4
    for (int j = 0; j < CHM; ++j) {
        float4 p  = pos[j];
        float dot = fmaf(x1, p.x, fmaf(y1, p.y, z1 * p.z));
        float d   = fmaf(-2.f, dot, n1 + p.w);
        // strict < keeps earliest index on ties (matches jax top_k)
        if (d < d2) {
            if (d < d1) {
                d2 = d1; i2 = i1;
                if (d < d0) { d1 = d0; i1 = i0; d0 = d; i0 = jb + j; }
                else        { d1 = d;  i1 = jb + j; }
            } else { d2 = d; i2 = jb + j; }
        }
    }
    const size_t base = (size_t)q * (NCH * 3) + c * 3;
    cand_d[base] = d0; cand_d[base + 1] = d1; cand_d[base + 2] = d2;
    cand_i[base] = i0; cand_i[base + 1] = i1; cand_i[base + 2] = i2;
}

// ---------------------------------------------------------------------------
// KNN stage 2: merge 24 candidates -> top-3, weights, then cooperative
// gather + concat -> xb (bf16 [R_TOT x CIN]).  grid = R_TOT/QPB = 1024.
// ---------------------------------------------------------------------------
__global__ __launch_bounds__(256) void interp_gather(
    const float* __restrict__ p1,     const float* __restrict__ p2,
    const float* __restrict__ cand_d, const int* __restrict__ cand_i,
    __bf16* __restrict__ xb) {
    __shared__ float wgt[QPB * 3];
    __shared__ int   ids[QPB * 3];

    const int tid = threadIdx.x;
    const int b   = blockIdx.x >> 7;            // 128 blocks per batch
    const int q0  = (blockIdx.x & 127) * QPB;   // query offset within batch

    if (tid < QPB) {
        const int q = b * N_Q + q0 + tid;
        const float* cd = cand_d + (size_t)q * (NCH * 3);
        const int*   ci = cand_i + (size_t)q * (NCH * 3);
        float d0 = 3.4e38f, d1 = 3.4e38f, d2 = 3.4e38f;
        int   i0 = 0, i1 = 0, i2 = 0;
        // chunk-ascending insertion, strict <  ->  global lowest-index ties
#pragma unroll
        for (int t = 0; t < NCH * 3; ++t) {
            float d = cd[t]; int i = ci[t];
            if (d < d2) {
                if (d < d1) {
                    d2 = d1; i2 = i1;
                    if (d < d0) { d1 = d0; i1 = i0; d0 = d; i0 = i; }
                    else        { d1 = d;  i1 = i; }
                } else { d2 = d; i2 = i; }
            }
        }
        float r0 = 1.f / (d0 + 1e-8f), r1 = 1.f / (d1 + 1e-8f), r2 = 1.f / (d2 + 1e-8f);
        float rs = 1.f / (r0 + r1 + r2);
        wgt[tid * 3] = r0 * rs; wgt[tid * 3 + 1] = r1 * rs; wgt[tid * 3 + 2] = r2 * rs;
        ids[tid * 3] = i0;      ids[tid * 3 + 1] = i1;      ids[tid * 3 + 2] = i2;
    }
    __syncthreads();

    // wave-per-query cooperative gather (coalesced 1KB row reads)
    const int wave = tid >> 6, lane = tid & 63;
    const float* p2b = p2 + (size_t)b * M_PT * C2;
    const float* p1b = p1 + (size_t)(b * N_Q + q0) * C1;
    __bf16* outp = xb + (size_t)(b * N_Q + q0) * CIN;
    for (int qq = wave; qq < QPB; qq += 4) {
        float w0 = wgt[qq * 3], w1 = wgt[qq * 3 + 1], w2 = wgt[qq * 3 + 2];
        int   j0 = ids[qq * 3], j1 = ids[qq * 3 + 1], j2 = ids[qq * 3 + 2];
        const float4* ra = (const float4*)(p2b + (size_t)j0 * C2);
        const float4* rb = (const float4*)(p2b + (size_t)j1 * C2);
        const float4* rc = (const float4*)(p2b + (size_t)j2 * C2);
        float4 va = ra[lane], vb = rb[lane], vc = rc[lane];
        bf16x4 o;
        o[0] = (__bf16)(w0 * va.x + w1 * vb.x + w2 * vc.x);
        o[1] = (__bf16)(w0 * va.y + w1 * vb.y + w2 * vc.y);
        o[2] = (__bf16)(w0 * va.z + w1 * vb.z + w2 * vc.z);
        o[3] = (__bf16)(w0 * va.w + w1 * vb.w + w2 * vc.w);
        *(bf16x4*)(outp + (size_t)qq * CIN + C1 + lane * 4) = o;
        float2 pv = ((const float2*)(p1b + (size_t)qq * C1))[lane];
        bf16x2 o2; o2[0] = (__bf16)pv.x; o2[1] = (__bf16)pv.y;
        *(bf16x2*)(outp + (size_t)qq * CIN + lane * 2) = o2;
    }
}

// ---------------------------------------------------------------------------
// bf16 MFMA GEMM: C[r,o] = sum_k A[r,k]*Bw[o,k]   (both K-major, "NT")
// m97 structure: 128x128 tile, 4 waves each 64x64, BK=32, global_load_lds x16B
// grid: (R_TOT/128)*(H_OUT/128) = 1024 blocks of 256
// ---------------------------------------------------------------------------
template <int K, bool OUT_BF16>
__global__ __launch_bounds__(256, 2) void gemm_bt(const __bf16* __restrict__ A,
                                                  const __bf16* __restrict__ Bw,
                                                  void* __restrict__ Cout) {
    __shared__ __attribute__((aligned(16))) __bf16 As[128 * 32];
    __shared__ __attribute__((aligned(16))) __bf16 Bs[128 * 32];
    const int tid  = threadIdx.x;
    const int wave = tid >> 6, lane = tid & 63;
    const int wm = wave >> 1, wn = wave & 1;
    const int quad = lane >> 4, r16 = lane & 15;
    const int bx = blockIdx.x & 1, by = blockIdx.x >> 1;
    const int l4 = lane >> 2, lk = (lane & 3) * 8;

    f32x4 acc[4][4] = {};

    const __bf16* gA = A  + (size_t)(by * 128 + wave * 32 + l4) * K + lk;
    const __bf16* gB = Bw + (size_t)(bx * 128 + wave * 32 + l4) * K + lk;
    char* lA = (char*)As + wave * 2048;
    char* lB = (char*)Bs + wave * 2048;

    for (int k0 = 0; k0 < K; k0 += 32) {
        async_copy16(gA + k0,                  lA);
        async_copy16(gA + k0 + (size_t)16 * K, lA + 1024);
        async_copy16(gB + k0,                  lB);
        async_copy16(gB + k0 + (size_t)16 * K, lB + 1024);
        __syncthreads();

        bf16x8 af[4], bf[4];
#pragma unroll
        for (int t = 0; t < 4; ++t)
            af[t] = *(const bf16x8*)(As + (wm * 64 + t * 16 + r16) * 32 + quad * 8);
#pragma unroll
        for (int u = 0; u < 4; ++u)
            bf[u] = *(const bf16x8*)(Bs + (wn * 64 + u * 16 + r16) * 32 + quad * 8);
#pragma unroll
        for (int t = 0; t < 4; ++t)
#pragma unroll
            for (int u = 0; u < 4; ++u)
                acc[t][u] = __builtin_amdgcn_mfma_f32_16x16x32_bf16(af[t], bf[u], acc[t][u], 0, 0, 0);
        __syncthreads();
    }

    // epilogue: C/D layout col=lane&15, row=(lane>>4)*4+reg [m89-verified]
#pragma unroll
    for (int t = 0; t < 4; ++t) {
#pragma unroll
        for (int u = 0; u < 4; ++u) {
            const int col = bx * 128 + wn * 64 + u * 16 + r16;
#pragma unroll
            for (int r = 0; r < 4; ++r) {
                const int row = by * 128 + wm * 64 + t * 16 + quad * 4 + r;
                if (OUT_BF16)
                    ((__bf16*)Cout)[(size_t)row * H_OUT + col] = (__bf16)acc[t][u][r];
                else
                    ((float*)Cout)[(size_t)row * H_OUT + col] = acc[t][u][r];
            }
        }
    }
}

// ---------------------------------------------------------------------------
// BatchNorm batch-stats, deterministic 2-stage
// ---------------------------------------------------------------------------
__global__ __launch_bounds__(256) void stats_bf16(const __bf16* __restrict__ y,
                                                  float* __restrict__ part) {
    const int c = threadIdx.x;
    const __bf16* p = y + (size_t)blockIdx.x * 256 * H_OUT + c;
    float s = 0.f, q = 0.f;
    for (int r = 0; r < 256; ++r) {
        float v = (float)p[(size_t)r * H_OUT];
        s += v; q = fmaf(v, v, q);
    }
    part[blockIdx.x * 512 + c]       = s;
    part[blockIdx.x * 512 + 256 + c] = q;
}

__global__ __launch_bounds__(256) void stats_f32(const float* __restrict__ y,
                                                 float* __restrict__ part) {
    const int c = threadIdx.x;
    const float* p = y + (size_t)blockIdx.x * 256 * H_OUT + c;
    float s = 0.f, q = 0.f;
    for (int r = 0; r < 256; ++r) {
        float v = p[(size_t)r * H_OUT];
        s += v; q = fmaf(v, v, q);
    }
    part[blockIdx.x * 512 + c]       = s;
    part[blockIdx.x * 512 + 256 + c] = q;
}

// stage2: fold partials -> per-channel scale/shift.  Bias b cancels in BN.
__global__ __launch_bounds__(256) void bn_finalize(const float* __restrict__ part,
                                                   const float* __restrict__ gamma,
                                                   const float* __restrict__ beta,
                                                   float* __restrict__ sc,
                                                   float* __restrict__ sh) {
    const int c = threadIdx.x;
    float s = 0.f, q = 0.f;
    for (int p = 0; p < 256; ++p) {
        s += part[p * 512 + c];
        q += part[p * 512 + 256 + c];
    }
    const float inv = 1.f / (float)R_TOT;
    float mean = s * inv;
    float var  = q * inv - mean * mean;
    float a    = gamma[c] * rsqrtf(var + 1e-5f);
    sc[c] = a;
    sh[c] = beta[c] - mean * a;
}

// ---------------------------------------------------------------------------
// apply BN+ReLU in place
// ---------------------------------------------------------------------------
__global__ __launch_bounds__(256) void apply_bf16(__bf16* __restrict__ y,
                                                  const float* __restrict__ sc,
                                                  const float* __restrict__ sh) {
    __shared__ float scs[256], shs[256];
    scs[threadIdx.x] = sc[threadIdx.x];
    shs[threadIdx.x] = sh[threadIdx.x];
    __syncthreads();
    size_t i = ((size_t)blockIdx.x * 256 + threadIdx.x) * 8;
    int c0 = (int)(i & 255);
    bf16x8 v = *(const bf16x8*)(y + i);
#pragma unroll
    for (int e = 0; e < 8; ++e) {
        float f = fmaf((float)v[e], scs[c0 + e], shs[c0 + e]);
        v[e] = (__bf16)fmaxf(f, 0.f);
    }
    *(bf16x8*)(y + i) = v;
}

__global__ __launch_bounds__(256) void apply_f32(float* __restrict__ y,
                                                 const float* __restrict__ sc,
                                                 const float* __restrict__ sh) {
    __shared__ float scs[256], shs[256];
    scs[threadIdx.x] = sc[threadIdx.x];
    shs[threadIdx.x] = sh[threadIdx.x];
    __syncthreads();
    size_t i = ((size_t)blockIdx.x * 256 + threadIdx.x) * 4;
    int c0 = (int)(i & 255);
    float4 v = *(const float4*)(y + i);
    v.x = fmaxf(fmaf(v.x, scs[c0 + 0], shs[c0 + 0]), 0.f);
    v.y = fmaxf(fmaf(v.y, scs[c0 + 1], shs[c0 + 1]), 0.f);
    v.z = fmaxf(fmaf(v.z, scs[c0 + 2], shs[c0 + 2]), 0.f);
    v.w = fmaxf(fmaf(v.w, scs[c0 + 3], shs[c0 + 3]), 0.f);
    *(float4*)(y + i) = v;
}

// ---------------------------------------------------------------------------
extern "C" void kernel_launch(void* const* d_in, const int* in_sizes, int n_in,
                              void* d_out, int out_size, void* d_ws, size_t ws_size,
                              hipStream_t stream) {
    const float* xyz1 = (const float*)d_in[0];
    const float* xyz2 = (const float*)d_in[1];
    const float* p1   = (const float*)d_in[2];
    const float* p2   = (const float*)d_in[3];
    const float* W1   = (const float*)d_in[4];
    // d_in[5] = b1  (cancels in batch-norm)
    const float* g1   = (const float*)d_in[6];
    const float* be1  = (const float*)d_in[7];
    const float* W2   = (const float*)d_in[8];
    // d_in[9] = b2  (cancels in batch-norm)
    const float* g2   = (const float*)d_in[10];
    const float* be2  = (const float*)d_in[11];
    float* out = (float*)d_out;

    // workspace layout (16B aligned); cand_* overlays the y1b region (it is
    // consumed by interp_gather before GEMM1 writes y1b).  total ~84.7 MB
    char* ws = (char*)d_ws;
    __bf16* xb     = (__bf16*)(ws);                    // 65536*384*2 = 50331648
    __bf16* y1b    = (__bf16*)(ws + 50331648);         // 65536*256*2 = 33554432
    float*  cand_d = (float*) (ws + 50331648);         // 65536*24*4  =  6291456
    int*    cand_i = (int*)   (ws + 56623104);         // 65536*24*4  =  6291456
    __bf16* wb1    = (__bf16*)(ws + 83886080);         // 256*384*2
    __bf16* wb2    = (__bf16*)(ws + 84082688);         // 256*256*2
    float*  part   = (float*) (ws + 84213760);         // 256*512*4
    float*  sc1    = (float*) (ws + 84738048);
    float*  sh1    = sc1 + 256;
    float*  sc2    = sc1 + 512;
    float*  sh2    = sc1 + 768;

    f2bf<<<384, 256, 0, stream>>>(W1, wb1, H_OUT * CIN);
    f2bf<<<256, 256, 0, stream>>>(W2, wb2, H_OUT * H_OUT);

    knn_partial<<<B_SZ * 32 * NCH, 256, 0, stream>>>(xyz1, xyz2, cand_d, cand_i);
    interp_gather<<<R_TOT / QPB, 256, 0, stream>>>(p1, p2, cand_d, cand_i, xb);

    gemm_bt<CIN, true><<<1024, 256, 0, stream>>>(xb, wb1, (void*)y1b);
    stats_bf16<<<256, 256, 0, stream>>>(y1b, part);
    bn_finalize<<<1, 256, 0, stream>>>(part, g1, be1, sc1, sh1);
    apply_bf16<<<8192, 256, 0, stream>>>(y1b, sc1, sh1);

    gemm_bt<H_OUT, false><<<1024, 256, 0, stream>>>(y1b, wb2, (void*)out);
    stats_f32<<<256, 256, 0, stream>>>(out, part);
    bn_finalize<<<1, 256, 0, stream>>>(part, g2, be2, sc2, sh2);
    apply_f32<<<16384, 256, 0, stream>>>(out, sc2, sh2);
}

// Round 3
// 320.778 us; speedup vs baseline: 1.4879x; 1.0303x over previous
//
#include <hip/hip_runtime.h>
#include <hip/hip_bf16.h>
#include <stdint.h>

// Problem constants (fixed by setup_inputs)
#define B_SZ  8
#define N_Q   8192
#define M_PT  2048
#define C1    128
#define C2    256
#define CIN   384      // C1 + C2
#define H_OUT 256
#define R_TOT 65536    // B_SZ * N_Q

#define NCH   8              // KNN chunks over M
#define CHM   (M_PT / NCH)   // 256 points per chunk
#define QPB   32             // queries per gather block

typedef __bf16 bf16x8 __attribute__((ext_vector_type(8)));
typedef __bf16 bf16x4 __attribute__((ext_vector_type(4)));
typedef __bf16 bf16x2 __attribute__((ext_vector_type(2)));
typedef float  f32x4  __attribute__((ext_vector_type(4)));

// Async global->LDS, 16B per lane. LDS dest is wave-uniform base + lane*16.
__device__ __forceinline__ void async_copy16(const void* g, void* l) {
    __builtin_amdgcn_global_load_lds(
        (const __attribute__((address_space(1))) unsigned int*)g,
        (__attribute__((address_space(3))) unsigned int*)l,
        16, 0, 0);
}

// ---------------------------------------------------------------------------
// fp32 -> bf16 convert, both weight matrices in one dispatch
// ---------------------------------------------------------------------------
__global__ __launch_bounds__(256) void f2bf2(const float* __restrict__ a, int na,
                                             const float* __restrict__ b, int nb,
                                             __bf16* __restrict__ oa,
                                             __bf16* __restrict__ ob) {
    int i = blockIdx.x * 256 + threadIdx.x;
    if (i < na)            oa[i] = (__bf16)a[i];
    else if (i - na < nb)  ob[i - na] = (__bf16)b[i - na];
}

// ---------------------------------------------------------------------------
// KNN stage 1: per-chunk top-3.  grid = B*32*NCH = 2048 blocks of 256.
// Branchless insertion: values via min/med3 (sorted invariant d0<=d1<=d2),
// indices via cndmask ternaries.  ~17 VALU/pair vs ~35 for the branchy form
// (R2 measured 35 ops/pair: wave-any divergence fired ~50% of iters).
// Distance formula bit-identical to R2 (proven tie behavior).
// ---------------------------------------------------------------------------
__global__ __launch_bounds__(256) void knn_partial(
    const float* __restrict__ xyz1, const float* __restrict__ xyz2,
    float* __restrict__ cand_d, int* __restrict__ cand_i) {
    __shared__ float4 pos[CHM];

    const int tid = threadIdx.x;
    const int c   = blockIdx.x & (NCH - 1);
    const int qb  = (blockIdx.x >> 3) & 31;
    const int b   = blockIdx.x >> 8;

    {
        const float* x2 = xyz2 + ((size_t)b * M_PT + c * CHM) * 3;
        float x = x2[tid * 3], y = x2[tid * 3 + 1], z = x2[tid * 3 + 2];
        pos[tid] = make_float4(x, y, z, x * x + y * y + z * z);
    }
    __syncthreads();

    const int q = b * N_Q + qb * 256 + tid;
    const float* q1 = xyz1 + (size_t)q * 3;
    float x1 = q1[0], y1 = q1[1], z1 = q1[2];
    float n1 = x1 * x1 + y1 * y1 + z1 * z1;
    float d0 = 3.4e38f, d1 = 3.4e38f, d2 = 3.4e38f;
    int   i0 = 0, i1 = 0, i2 = 0;
    const int jb = c * CHM;
#pragma unroll 8
    for (int j = 0; j < CHM; ++j) {
        float4 p  = pos[j];
        float dot = fmaf(x1, p.x, fmaf(y1, p.y, z1 * p.z));
        float d   = fmaf(-2.f, dot, n1 + p.w);
        const int jj = jb + j;
        // strict < keeps earliest index on ties (matches jax top_k)
        const bool c2 = d < d2, c1 = d < d1, c0 = d < d0;
        const int ni2 = c1 ? i1 : (c2 ? jj : i2);
        const int ni1 = c0 ? i0 : (c1 ? jj : i1);
        const int ni0 = c0 ? jj : i0;
        const float nd2 = fminf(fmaxf(d, d1), d2);
        const float nd1 = __builtin_amdgcn_fmed3f(d, d0, d1);
        const float nd0 = fminf(d, d0);
        i2 = ni2; i1 = ni1; i0 = ni0;
        d2 = nd2; d1 = nd1; d0 = nd0;
    }
    const size_t base = (size_t)q * (NCH * 3) + c * 3;
    cand_d[base] = d0; cand_d[base + 1] = d1; cand_d[base + 2] = d2;
    cand_i[base] = i0; cand_i[base + 1] = i1; cand_i[base + 2] = i2;
}

// ---------------------------------------------------------------------------
// KNN stage 2: merge 24 candidates -> top-3, weights, then cooperative
// gather + concat -> xb (bf16 [R_TOT x CIN]).  grid = R_TOT/QPB = 2048.
// ---------------------------------------------------------------------------
__global__ __launch_bounds__(256) void interp_gather(
    const float* __restrict__ p1,     const float* __restrict__ p2,
    const float* __restrict__ cand_d, const int* __restrict__ cand_i,
    __bf16* __restrict__ xb) {
    __shared__ float wgt[QPB * 3];
    __shared__ int   ids[QPB * 3];

    const int tid = threadIdx.x;
    const int b   = blockIdx.x >> 8;            // 256 blocks per batch
    const int q0  = (blockIdx.x & 255) * QPB;   // query offset within batch

    if (tid < QPB) {
        const int q = b * N_Q + q0 + tid;
        const float* cd = cand_d + (size_t)q * (NCH * 3);
        const int*   ci = cand_i + (size_t)q * (NCH * 3);
        float d0 = 3.4e38f, d1 = 3.4e38f, d2 = 3.4e38f;
        int   i0 = 0, i1 = 0, i2 = 0;
        // chunk-ascending insertion, strict <  ->  global lowest-index ties
#pragma unroll
        for (int t = 0; t < NCH * 3; ++t) {
            float d = cd[t]; int i = ci[t];
            const bool c2 = d < d2, c1 = d < d1, c0 = d < d0;
            const int ni2 = c1 ? i1 : (c2 ? i : i2);
            const int ni1 = c0 ? i0 : (c1 ? i : i1);
            const int ni0 = c0 ? i : i0;
            const float nd2 = fminf(fmaxf(d, d1), d2);
            const float nd1 = __builtin_amdgcn_fmed3f(d, d0, d1);
            const float nd0 = fminf(d, d0);
            i2 = ni2; i1 = ni1; i0 = ni0;
            d2 = nd2; d1 = nd1; d0 = nd0;
        }
        float r0 = 1.f / (d0 + 1e-8f), r1 = 1.f / (d1 + 1e-8f), r2 = 1.f / (d2 + 1e-8f);
        float rs = 1.f / (r0 + r1 + r2);
        wgt[tid * 3] = r0 * rs; wgt[tid * 3 + 1] = r1 * rs; wgt[tid * 3 + 2] = r2 * rs;
        ids[tid * 3] = i0;      ids[tid * 3 + 1] = i1;      ids[tid * 3 + 2] = i2;
    }
    __syncthreads();

    // wave-per-query cooperative gather (coalesced 1KB row reads)
    const int wave = tid >> 6, lane = tid & 63;
    const float* p2b = p2 + (size_t)b * M_PT * C2;
    const float* p1b = p1 + (size_t)(b * N_Q + q0) * C1;
    __bf16* outp = xb + (size_t)(b * N_Q + q0) * CIN;
    for (int qq = wave; qq < QPB; qq += 4) {
        float w0 = wgt[qq * 3], w1 = wgt[qq * 3 + 1], w2 = wgt[qq * 3 + 2];
        int   j0 = ids[qq * 3], j1 = ids[qq * 3 + 1], j2 = ids[qq * 3 + 2];
        const float4* ra = (const float4*)(p2b + (size_t)j0 * C2);
        const float4* rb = (const float4*)(p2b + (size_t)j1 * C2);
        const float4* rc = (const float4*)(p2b + (size_t)j2 * C2);
        float4 va = ra[lane], vb = rb[lane], vc = rc[lane];
        bf16x4 o;
        o[0] = (__bf16)(w0 * va.x + w1 * vb.x + w2 * vc.x);
        o[1] = (__bf16)(w0 * va.y + w1 * vb.y + w2 * vc.y);
        o[2] = (__bf16)(w0 * va.z + w1 * vb.z + w2 * vc.z);
        o[3] = (__bf16)(w0 * va.w + w1 * vb.w + w2 * vc.w);
        *(bf16x4*)(outp + (size_t)qq * CIN + C1 + lane * 4) = o;
        float2 pv = ((const float2*)(p1b + (size_t)qq * C1))[lane];
        bf16x2 o2; o2[0] = (__bf16)pv.x; o2[1] = (__bf16)pv.y;
        *(bf16x2*)(outp + (size_t)qq * CIN + lane * 2) = o2;
    }
}

// ---------------------------------------------------------------------------
// bf16 MFMA GEMM + fused BN-stats partials: C[r,o] = sum_k A[r,k]*Bw[o,k]
// m97 structure: 128x128 tile, 4 waves each 64x64, BK=32, global_load_lds x16B
// Epilogue additionally emits per-block per-channel (sum, sumsq) partials
// (deterministic; folded by bn_finalize).  grid: 1024 blocks of 256.
// ---------------------------------------------------------------------------
template <int K, bool OUT_BF16>
__global__ __launch_bounds__(256, 2) void gemm_bt(const __bf16* __restrict__ A,
                                                  const __bf16* __restrict__ Bw,
                                                  void* __restrict__ Cout,
                                                  float* __restrict__ partS,
                                                  float* __restrict__ partQ) {
    __shared__ __attribute__((aligned(16))) __bf16 As[128 * 32];
    __shared__ __attribute__((aligned(16))) __bf16 Bs[128 * 32];
    const int tid  = threadIdx.x;
    const int wave = tid >> 6, lane = tid & 63;
    const int wm = wave >> 1, wn = wave & 1;
    const int quad = lane >> 4, r16 = lane & 15;
    const int bx = blockIdx.x & 1, by = blockIdx.x >> 1;
    const int l4 = lane >> 2, lk = (lane & 3) * 8;

    f32x4 acc[4][4] = {};

    const __bf16* gA = A  + (size_t)(by * 128 + wave * 32 + l4) * K + lk;
    const __bf16* gB = Bw + (size_t)(bx * 128 + wave * 32 + l4) * K + lk;
    char* lA = (char*)As + wave * 2048;
    char* lB = (char*)Bs + wave * 2048;

    for (int k0 = 0; k0 < K; k0 += 32) {
        async_copy16(gA + k0,                  lA);
        async_copy16(gA + k0 + (size_t)16 * K, lA + 1024);
        async_copy16(gB + k0,                  lB);
        async_copy16(gB + k0 + (size_t)16 * K, lB + 1024);
        __syncthreads();

        bf16x8 af[4], bf[4];
#pragma unroll
        for (int t = 0; t < 4; ++t)
            af[t] = *(const bf16x8*)(As + (wm * 64 + t * 16 + r16) * 32 + quad * 8);
#pragma unroll
        for (int u = 0; u < 4; ++u)
            bf[u] = *(const bf16x8*)(Bs + (wn * 64 + u * 16 + r16) * 32 + quad * 8);
#pragma unroll
        for (int t = 0; t < 4; ++t)
#pragma unroll
            for (int u = 0; u < 4; ++u)
                acc[t][u] = __builtin_amdgcn_mfma_f32_16x16x32_bf16(af[t], bf[u], acc[t][u], 0, 0, 0);
        __syncthreads();
    }

    // C/D layout col=lane&15, row=(lane>>4)*4+reg [m89-verified]
#pragma unroll
    for (int t = 0; t < 4; ++t) {
#pragma unroll
        for (int u = 0; u < 4; ++u) {
            const int col = bx * 128 + wn * 64 + u * 16 + r16;
#pragma unroll
            for (int r = 0; r < 4; ++r) {
                const int row = by * 128 + wm * 64 + t * 16 + quad * 4 + r;
                if (OUT_BF16)
                    ((__bf16*)Cout)[(size_t)row * H_OUT + col] = (__bf16)acc[t][u][r];
                else
                    ((float*)Cout)[(size_t)row * H_OUT + col] = acc[t][u][r];
            }
        }
    }

    // fused BN-stats partials (reuse As as 8 KB reduction scratch; last
    // K-loop barrier already ordered all LDS reads before this point)
    float* redS = (float*)As;          // [col(128)][slot(8)]
    float* redQ = ((float*)As) + 1024;
    const int slot = wm * 4 + quad;
#pragma unroll
    for (int u = 0; u < 4; ++u) {
        float s = 0.f, qq = 0.f;
#pragma unroll
        for (int t = 0; t < 4; ++t)
#pragma unroll
            for (int r = 0; r < 4; ++r) { float v = acc[t][u][r]; s += v; qq = fmaf(v, v, qq); }
        const int col = wn * 64 + u * 16 + r16;
        redS[col * 8 + slot] = s;
        redQ[col * 8 + slot] = qq;
    }
    __syncthreads();
    if (tid < 128) {
        float s = 0.f, qq = 0.f;
#pragma unroll
        for (int k = 0; k < 8; ++k) { s += redS[tid * 8 + k]; qq += redQ[tid * 8 + k]; }
        partS[(size_t)blockIdx.x * 128 + tid] = s;
        partQ[(size_t)blockIdx.x * 128 + tid] = qq;
    }
}

// ---------------------------------------------------------------------------
// fold 512 per-block partials -> per-channel scale/shift. Bias b cancels in BN.
// channel c lives in blocks bid = p*2 + (c>>7), entry (c&127).
// ---------------------------------------------------------------------------
__global__ __launch_bounds__(256) void bn_finalize(const float* __restrict__ pS,
                                                   const float* __restrict__ pQ,
                                                   const float* __restrict__ gamma,
                                                   const float* __restrict__ beta,
                                                   float* __restrict__ sc,
                                                   float* __restrict__ sh) {
    const int c = threadIdx.x;
    const int half = c >> 7, lo = c & 127;
    float s = 0.f, q = 0.f;
    for (int p = 0; p < 512; ++p) {
        const size_t off = (size_t)(p * 2 + half) * 128 + lo;
        s += pS[off];
        q += pQ[off];
    }
    const float inv = 1.f / (float)R_TOT;
    float mean = s * inv;
    float var  = q * inv - mean * mean;
    float a    = gamma[c] * rsqrtf(var + 1e-5f);
    sc[c] = a;
    sh[c] = beta[c] - mean * a;
}

// ---------------------------------------------------------------------------
// apply BN+ReLU in place
// ---------------------------------------------------------------------------
__global__ __launch_bounds__(256) void apply_bf16(__bf16* __restrict__ y,
                                                  const float* __restrict__ sc,
                                                  const float* __restrict__ sh) {
    __shared__ float scs[256], shs[256];
    scs[threadIdx.x] = sc[threadIdx.x];
    shs[threadIdx.x] = sh[threadIdx.x];
    __syncthreads();
    size_t i = ((size_t)blockIdx.x * 256 + threadIdx.x) * 8;
    int c0 = (int)(i & 255);
    bf16x8 v = *(const bf16x8*)(y + i);
#pragma unroll
    for (int e = 0; e < 8; ++e) {
        float f = fmaf((float)v[e], scs[c0 + e], shs[c0 + e]);
        v[e] = (__bf16)fmaxf(f, 0.f);
    }
    *(bf16x8*)(y + i) = v;
}

__global__ __launch_bounds__(256) void apply_f32(float* __restrict__ y,
                                                 const float* __restrict__ sc,
                                                 const float* __restrict__ sh) {
    __shared__ float scs[256], shs[256];
    scs[threadIdx.x] = sc[threadIdx.x];
    shs[threadIdx.x] = sh[threadIdx.x];
    __syncthreads();
    size_t i = ((size_t)blockIdx.x * 256 + threadIdx.x) * 4;
    int c0 = (int)(i & 255);
    float4 v = *(const float4*)(y + i);
    v.x = fmaxf(fmaf(v.x, scs[c0 + 0], shs[c0 + 0]), 0.f);
    v.y = fmaxf(fmaf(v.y, scs[c0 + 1], shs[c0 + 1]), 0.f);
    v.z = fmaxf(fmaf(v.z, scs[c0 + 2], shs[c0 + 2]), 0.f);
    v.w = fmaxf(fmaf(v.w, scs[c0 + 3], shs[c0 + 3]), 0.f);
    *(float4*)(y + i) = v;
}

// ---------------------------------------------------------------------------
extern "C" void kernel_launch(void* const* d_in, const int* in_sizes, int n_in,
                              void* d_out, int out_size, void* d_ws, size_t ws_size,
                              hipStream_t stream) {
    const float* xyz1 = (const float*)d_in[0];
    const float* xyz2 = (const float*)d_in[1];
    const float* p1   = (const float*)d_in[2];
    const float* p2   = (const float*)d_in[3];
    const float* W1   = (const float*)d_in[4];
    // d_in[5] = b1  (cancels in batch-norm)
    const float* g1   = (const float*)d_in[6];
    const float* be1  = (const float*)d_in[7];
    const float* W2   = (const float*)d_in[8];
    // d_in[9] = b2  (cancels in batch-norm)
    const float* g2   = (const float*)d_in[10];
    const float* be2  = (const float*)d_in[11];
    float* out = (float*)d_out;

    // workspace layout (16B aligned).  cand_* overlays y1b (consumed by
    // interp_gather before GEMM1 writes y1b).  GEMM1 stats partials live in
    // d_out (dead until GEMM2); GEMM2 stats partials live in xb (dead after
    // GEMM1).  Footprint unchanged vs R2 (~84.7 MB).
    char* ws = (char*)d_ws;
    __bf16* xb     = (__bf16*)(ws);                    // 65536*384*2 = 50331648
    __bf16* y1b    = (__bf16*)(ws + 50331648);         // 65536*256*2 = 33554432
    float*  cand_d = (float*) (ws + 50331648);         // 65536*24*4  =  6291456
    int*    cand_i = (int*)   (ws + 56623104);         // 65536*24*4  =  6291456
    __bf16* wb1    = (__bf16*)(ws + 83886080);         // 256*384*2
    __bf16* wb2    = (__bf16*)(ws + 84082688);         // 256*256*2
    float*  sc1    = (float*) (ws + 84213760);
    float*  sh1    = sc1 + 256;
    float*  sc2    = sc1 + 512;
    float*  sh2    = sc1 + 768;

    float* partS1 = (float*)d_out;            // 1024*128*4 = 512 KB
    float* partQ1 = partS1 + 131072;          // another 512 KB (d_out is 64 MB)
    float* partS2 = (float*)ws;               // xb region, dead during GEMM2
    float* partQ2 = partS2 + 131072;

    f2bf2<<<640, 256, 0, stream>>>(W1, H_OUT * CIN, W2, H_OUT * H_OUT, wb1, wb2);

    knn_partial<<<B_SZ * 32 * NCH, 256, 0, stream>>>(xyz1, xyz2, cand_d, cand_i);
    interp_gather<<<R_TOT / QPB, 256, 0, stream>>>(p1, p2, cand_d, cand_i, xb);

    gemm_bt<CIN, true><<<1024, 256, 0, stream>>>(xb, wb1, (void*)y1b, partS1, partQ1);
    bn_finalize<<<1, 256, 0, stream>>>(partS1, partQ1, g1, be1, sc1, sh1);
    apply_bf16<<<8192, 256, 0, stream>>>(y1b, sc1, sh1);

    gemm_bt<H_OUT, false><<<1024, 256, 0, stream>>>(y1b, wb2, (void*)out, partS2, partQ2);
    bn_finalize<<<1, 256, 0, stream>>>(partS2, partQ2, g2, be2, sc2, sh2);
    apply_f32<<<16384, 256, 0, stream>>>(out, sc2, sh2);
}

// Round 4
// 280.437 us; speedup vs baseline: 1.7019x; 1.1439x over previous
//
#include <hip/hip_runtime.h>
#include <hip/hip_bf16.h>
#include <stdint.h>

// Problem constants (fixed by setup_inputs)
#define B_SZ  8
#define N_Q   8192
#define M_PT  2048
#define C1    128
#define C2    256
#define CIN   384      // C1 + C2
#define H_OUT 256
#define R_TOT 65536    // B_SZ * N_Q

#define NCH   8              // KNN chunks over M
#define CHM   (M_PT / NCH)   // 256 points per chunk
#define QPB   32             // queries per gather block

typedef __bf16 bf16x8 __attribute__((ext_vector_type(8)));
typedef __bf16 bf16x4 __attribute__((ext_vector_type(4)));
typedef __bf16 bf16x2 __attribute__((ext_vector_type(2)));
typedef float  f32x4  __attribute__((ext_vector_type(4)));

// Async global->LDS, 16B per lane. LDS dest is wave-uniform base + lane*16.
__device__ __forceinline__ void async_copy16(const void* g, void* l) {
    __builtin_amdgcn_global_load_lds(
        (const __attribute__((address_space(1))) unsigned int*)g,
        (__attribute__((address_space(3))) unsigned int*)l,
        16, 0, 0);
}

// ---------------------------------------------------------------------------
// fp32 -> bf16 convert, both weight matrices in one dispatch
// ---------------------------------------------------------------------------
__global__ __launch_bounds__(256) void f2bf2(const float* __restrict__ a, int na,
                                             const float* __restrict__ b, int nb,
                                             __bf16* __restrict__ oa,
                                             __bf16* __restrict__ ob) {
    int i = blockIdx.x * 256 + threadIdx.x;
    if (i < na)            oa[i] = (__bf16)a[i];
    else if (i - na < nb)  ob[i - na] = (__bf16)b[i - na];
}

// ---------------------------------------------------------------------------
// KNN K1: values-only per-chunk top-3.  d' = |q-p|^2 - |q|^2 (monotone shift
// per query, so ordering matches).  Pure min/med3 network: 3 fma + 3 minmed
// per pair, NO compares/cndmasks (R3 showed index tracking 2x-bloats codegen).
// grid = B*32*NCH = 2048 blocks of 256.
// ---------------------------------------------------------------------------
__global__ __launch_bounds__(256) void knn_vals(
    const float* __restrict__ xyz1, const float* __restrict__ xyz2,
    float4* __restrict__ vals4) {
    __shared__ float4 pos[CHM];
    const int tid = threadIdx.x;
    const int c   = blockIdx.x & (NCH - 1);
    const int qb  = (blockIdx.x >> 3) & 31;
    const int b   = blockIdx.x >> 8;
    {   // stage (-2x, -2y, -2z, |p|^2) — MUST match knn_recover bitwise
        const float* x2 = xyz2 + ((size_t)b * M_PT + c * CHM) * 3;
        float x = x2[tid * 3], y = x2[tid * 3 + 1], z = x2[tid * 3 + 2];
        pos[tid] = make_float4(-2.f * x, -2.f * y, -2.f * z,
                               fmaf(x, x, fmaf(y, y, z * z)));
    }
    __syncthreads();

    const int q = b * N_Q + qb * 256 + tid;
    const float* q1 = xyz1 + (size_t)q * 3;
    float x1 = q1[0], y1 = q1[1], z1 = q1[2];
    float v0 = 3.4e38f, v1 = 3.4e38f, v2 = 3.4e38f;
#pragma unroll 8
    for (int j = 0; j < CHM; ++j) {
        float4 p = pos[j];
        float d  = fmaf(p.x, x1, fmaf(p.y, y1, fmaf(p.z, z1, p.w)));
        float n0 = fminf(d, v0);
        float n1 = __builtin_amdgcn_fmed3f(d, v0, v1);
        float n2 = __builtin_amdgcn_fmed3f(d, v1, v2);
        v0 = n0; v1 = n1; v2 = n2;
    }
    vals4[(size_t)c * R_TOT + q] = make_float4(v0, v1, v2, 0.f);
}

// ---------------------------------------------------------------------------
// KNN K2: merge 8 chunk-triples -> global (v0,v1,v2); compute interp weights
// (d_k = v_k + |q|^2, one extra rounding vs ref — negligible).  grid 256.
// ---------------------------------------------------------------------------
__global__ __launch_bounds__(256) void knn_merge(
    const float4* __restrict__ vals4, const float* __restrict__ xyz1,
    float4* __restrict__ v4, float4* __restrict__ w4) {
    const int q = blockIdx.x * 256 + threadIdx.x;
    float v0 = 3.4e38f, v1 = 3.4e38f, v2 = 3.4e38f;
#pragma unroll
    for (int c = 0; c < NCH; ++c) {
        float4 t = vals4[(size_t)c * R_TOT + q];
#pragma unroll
        for (int k = 0; k < 3; ++k) {
            float d  = (k == 0) ? t.x : (k == 1) ? t.y : t.z;
            float n0 = fminf(d, v0);
            float n1 = __builtin_amdgcn_fmed3f(d, v0, v1);
            float n2 = __builtin_amdgcn_fmed3f(d, v1, v2);
            v0 = n0; v1 = n1; v2 = n2;
        }
    }
    const float* q1 = xyz1 + (size_t)q * 3;
    float x1 = q1[0], y1 = q1[1], z1 = q1[2];
    float n1q = fmaf(x1, x1, fmaf(y1, y1, z1 * z1));
    float r0 = 1.f / ((v0 + n1q) + 1e-8f);
    float r1 = 1.f / ((v1 + n1q) + 1e-8f);
    float r2 = 1.f / ((v2 + n1q) + 1e-8f);
    float rs = 1.f / (r0 + r1 + r2);
    v4[q] = make_float4(v0, v1, v2, 0.f);
    w4[q] = make_float4(r0 * rs, r1 * rs, r2 * rs, 0.f);
}

// ---------------------------------------------------------------------------
// KNN K3: index recovery.  Recompute d' bitwise-identically; match equality
// against global (v0,v1,v2).  Hit rate 3/2048/lane -> wave-any ~9%: the
// exec-masked body is rarely executed.  grid = 2048 blocks of 256.
// ---------------------------------------------------------------------------
__global__ __launch_bounds__(256) void knn_recover(
    const float* __restrict__ xyz1, const float* __restrict__ xyz2,
    const float4* __restrict__ v4, int4* __restrict__ ci4) {
    __shared__ float4 pos[CHM];
    const int tid = threadIdx.x;
    const int c   = blockIdx.x & (NCH - 1);
    const int qb  = (blockIdx.x >> 3) & 31;
    const int b   = blockIdx.x >> 8;
    {   // identical staging to knn_vals
        const float* x2 = xyz2 + ((size_t)b * M_PT + c * CHM) * 3;
        float x = x2[tid * 3], y = x2[tid * 3 + 1], z = x2[tid * 3 + 2];
        pos[tid] = make_float4(-2.f * x, -2.f * y, -2.f * z,
                               fmaf(x, x, fmaf(y, y, z * z)));
    }
    __syncthreads();

    const int q = b * N_Q + qb * 256 + tid;
    const float* q1 = xyz1 + (size_t)q * 3;
    float x1 = q1[0], y1 = q1[1], z1 = q1[2];
    const float4 vv = v4[q];
    int i0 = 0x7fffffff, i1 = 0x7fffffff, i2 = 0x7fffffff;
    const int jb = c * CHM;
#pragma unroll 4
    for (int j = 0; j < CHM; ++j) {
        float4 p = pos[j];
        float d  = fmaf(p.x, x1, fmaf(p.y, y1, fmaf(p.z, z1, p.w)));
        if (d <= vv.z) {             // rare: exec-mask + execz skip
            const int jj = jb + j;   // j ascending -> min keeps earliest
            i0 = min(i0, (d == vv.x) ? jj : 0x7fffffff);
            i1 = min(i1, (d == vv.y) ? jj : 0x7fffffff);
            i2 = min(i2, (d == vv.z) ? jj : 0x7fffffff);
        }
    }
    ci4[(size_t)c * R_TOT + q] = make_int4(i0, i1, i2, 0);
}

// ---------------------------------------------------------------------------
// K4: fold chunk indices (global min per slot), then cooperative gather +
// concat -> xb (bf16 [R_TOT x CIN]).  grid = R_TOT/QPB = 2048.
// ---------------------------------------------------------------------------
__global__ __launch_bounds__(256) void interp_gather(
    const float* __restrict__ p1,  const float* __restrict__ p2,
    const int4* __restrict__ ci4,  const float4* __restrict__ w4,
    __bf16* __restrict__ xb) {
    __shared__ float wgt[QPB * 3];
    __shared__ int   ids[QPB * 3];

    const int tid = threadIdx.x;
    const int b   = blockIdx.x >> 8;            // 256 blocks per batch
    const int q0  = (blockIdx.x & 255) * QPB;

    if (tid < QPB) {
        const int q = b * N_Q + q0 + tid;
        int i0 = 0x7fffffff, i1 = 0x7fffffff, i2 = 0x7fffffff;
#pragma unroll
        for (int c = 0; c < NCH; ++c) {
            int4 t = ci4[(size_t)c * R_TOT + q];
            i0 = min(i0, t.x); i1 = min(i1, t.y); i2 = min(i2, t.z);
        }
        float4 w = w4[q];
        wgt[tid * 3] = w.x; wgt[tid * 3 + 1] = w.y; wgt[tid * 3 + 2] = w.z;
        ids[tid * 3] = i0;  ids[tid * 3 + 1] = i1;  ids[tid * 3 + 2] = i2;
    }
    __syncthreads();

    // wave-per-query cooperative gather (coalesced 1KB row reads)
    const int wave = tid >> 6, lane = tid & 63;
    const float* p2b = p2 + (size_t)b * M_PT * C2;
    const float* p1b = p1 + (size_t)(b * N_Q + q0) * C1;
    __bf16* outp = xb + (size_t)(b * N_Q + q0) * CIN;
    for (int qq = wave; qq < QPB; qq += 4) {
        float w0 = wgt[qq * 3], w1 = wgt[qq * 3 + 1], w2 = wgt[qq * 3 + 2];
        int   j0 = ids[qq * 3], j1 = ids[qq * 3 + 1], j2 = ids[qq * 3 + 2];
        const float4* ra = (const float4*)(p2b + (size_t)j0 * C2);
        const float4* rb = (const float4*)(p2b + (size_t)j1 * C2);
        const float4* rc = (const float4*)(p2b + (size_t)j2 * C2);
        float4 va = ra[lane], vb = rb[lane], vc = rc[lane];
        bf16x4 o;
        o[0] = (__bf16)(w0 * va.x + w1 * vb.x + w2 * vc.x);
        o[1] = (__bf16)(w0 * va.y + w1 * vb.y + w2 * vc.y);
        o[2] = (__bf16)(w0 * va.z + w1 * vb.z + w2 * vc.z);
        o[3] = (__bf16)(w0 * va.w + w1 * vb.w + w2 * vc.w);
        *(bf16x4*)(outp + (size_t)qq * CIN + C1 + lane * 4) = o;
        float2 pv = ((const float2*)(p1b + (size_t)qq * C1))[lane];
        bf16x2 o2; o2[0] = (__bf16)pv.x; o2[1] = (__bf16)pv.y;
        *(bf16x2*)(outp + (size_t)qq * CIN + lane * 2) = o2;
    }
}

// ---------------------------------------------------------------------------
// bf16 MFMA GEMM + fused BN-stats partials: C[r,o] = sum_k A[r,k]*Bw[o,k]
// m97 structure: 128x128 tile, 4 waves each 64x64, BK=32, global_load_lds x16B
// grid: 1024 blocks of 256.
// ---------------------------------------------------------------------------
template <int K, bool OUT_BF16>
__global__ __launch_bounds__(256, 2) void gemm_bt(const __bf16* __restrict__ A,
                                                  const __bf16* __restrict__ Bw,
                                                  void* __restrict__ Cout,
                                                  float* __restrict__ partS,
                                                  float* __restrict__ partQ) {
    __shared__ __attribute__((aligned(16))) __bf16 As[128 * 32];
    __shared__ __attribute__((aligned(16))) __bf16 Bs[128 * 32];
    const int tid  = threadIdx.x;
    const int wave = tid >> 6, lane = tid & 63;
    const int wm = wave >> 1, wn = wave & 1;
    const int quad = lane >> 4, r16 = lane & 15;
    const int bx = blockIdx.x & 1, by = blockIdx.x >> 1;
    const int l4 = lane >> 2, lk = (lane & 3) * 8;

    f32x4 acc[4][4] = {};

    const __bf16* gA = A  + (size_t)(by * 128 + wave * 32 + l4) * K + lk;
    const __bf16* gB = Bw + (size_t)(bx * 128 + wave * 32 + l4) * K + lk;
    char* lA = (char*)As + wave * 2048;
    char* lB = (char*)Bs + wave * 2048;

    for (int k0 = 0; k0 < K; k0 += 32) {
        async_copy16(gA + k0,                  lA);
        async_copy16(gA + k0 + (size_t)16 * K, lA + 1024);
        async_copy16(gB + k0,                  lB);
        async_copy16(gB + k0 + (size_t)16 * K, lB + 1024);
        __syncthreads();

        bf16x8 af[4], bf[4];
#pragma unroll
        for (int t = 0; t < 4; ++t)
            af[t] = *(const bf16x8*)(As + (wm * 64 + t * 16 + r16) * 32 + quad * 8);
#pragma unroll
        for (int u = 0; u < 4; ++u)
            bf[u] = *(const bf16x8*)(Bs + (wn * 64 + u * 16 + r16) * 32 + quad * 8);
#pragma unroll
        for (int t = 0; t < 4; ++t)
#pragma unroll
            for (int u = 0; u < 4; ++u)
                acc[t][u] = __builtin_amdgcn_mfma_f32_16x16x32_bf16(af[t], bf[u], acc[t][u], 0, 0, 0);
        __syncthreads();
    }

    // C/D layout col=lane&15, row=(lane>>4)*4+reg [m89-verified]
#pragma unroll
    for (int t = 0; t < 4; ++t) {
#pragma unroll
        for (int u = 0; u < 4; ++u) {
            const int col = bx * 128 + wn * 64 + u * 16 + r16;
#pragma unroll
            for (int r = 0; r < 4; ++r) {
                const int row = by * 128 + wm * 64 + t * 16 + quad * 4 + r;
                if (OUT_BF16)
                    ((__bf16*)Cout)[(size_t)row * H_OUT + col] = (__bf16)acc[t][u][r];
                else
                    ((float*)Cout)[(size_t)row * H_OUT + col] = acc[t][u][r];
            }
        }
    }

    // fused BN-stats partials (reuse As as 8 KB reduction scratch)
    float* redS = (float*)As;          // [col(128)][slot(8)]
    float* redQ = ((float*)As) + 1024;
    const int slot = wm * 4 + quad;
#pragma unroll
    for (int u = 0; u < 4; ++u) {
        float s = 0.f, qq = 0.f;
#pragma unroll
        for (int t = 0; t < 4; ++t)
#pragma unroll
            for (int r = 0; r < 4; ++r) { float v = acc[t][u][r]; s += v; qq = fmaf(v, v, qq); }
        const int col = wn * 64 + u * 16 + r16;
        redS[col * 8 + slot] = s;
        redQ[col * 8 + slot] = qq;
    }
    __syncthreads();
    if (tid < 128) {
        float s = 0.f, qq = 0.f;
#pragma unroll
        for (int k = 0; k < 8; ++k) { s += redS[tid * 8 + k]; qq += redQ[tid * 8 + k]; }
        partS[(size_t)blockIdx.x * 128 + tid] = s;
        partQ[(size_t)blockIdx.x * 128 + tid] = qq;
    }
}

// ---------------------------------------------------------------------------
// fold per-block partials -> per-channel scale/shift.  ONE BLOCK PER CHANNEL
// (R3's single-block version was latency-bound: 512 strided loads x ~300cyc).
// channel c lives in gemm-blocks bid = p*2 + (c>>7), entry (c&127); p<512.
// ---------------------------------------------------------------------------
__global__ __launch_bounds__(256) void bn_finalize(const float* __restrict__ pS,
                                                   const float* __restrict__ pQ,
                                                   const float* __restrict__ gamma,
                                                   const float* __restrict__ beta,
                                                   float* __restrict__ sc,
                                                   float* __restrict__ sh) {
    __shared__ float rs[256], rq[256];
    const int c = blockIdx.x;
    const int t = threadIdx.x;
    const int half = c >> 7, lo = c & 127;
    const size_t o1 = (size_t)(2 * t + half) * 128 + lo;
    const size_t o2 = (size_t)(2 * (t + 256) + half) * 128 + lo;
    rs[t] = pS[o1] + pS[o2];
    rq[t] = pQ[o1] + pQ[o2];
    __syncthreads();
    for (int k = 128; k > 0; k >>= 1) {
        if (t < k) { rs[t] += rs[t + k]; rq[t] += rq[t + k]; }
        __syncthreads();
    }
    if (t == 0) {
        const float inv = 1.f / (float)R_TOT;
        float mean = rs[0] * inv;
        float var  = rq[0] * inv - mean * mean;
        float a    = gamma[c] * rsqrtf(var + 1e-5f);
        sc[c] = a;
        sh[c] = beta[c] - mean * a;
    }
}

// ---------------------------------------------------------------------------
// apply BN+ReLU in place
// ---------------------------------------------------------------------------
__global__ __launch_bounds__(256) void apply_bf16(__bf16* __restrict__ y,
                                                  const float* __restrict__ sc,
                                                  const float* __restrict__ sh) {
    __shared__ float scs[256], shs[256];
    scs[threadIdx.x] = sc[threadIdx.x];
    shs[threadIdx.x] = sh[threadIdx.x];
    __syncthreads();
    size_t i = ((size_t)blockIdx.x * 256 + threadIdx.x) * 8;
    int c0 = (int)(i & 255);
    bf16x8 v = *(const bf16x8*)(y + i);
#pragma unroll
    for (int e = 0; e < 8; ++e) {
        float f = fmaf((float)v[e], scs[c0 + e], shs[c0 + e]);
        v[e] = (__bf16)fmaxf(f, 0.f);
    }
    *(bf16x8*)(y + i) = v;
}

__global__ __launch_bounds__(256) void apply_f32(float* __restrict__ y,
                                                 const float* __restrict__ sc,
                                                 const float* __restrict__ sh) {
    __shared__ float scs[256], shs[256];
    scs[threadIdx.x] = sc[threadIdx.x];
    shs[threadIdx.x] = sh[threadIdx.x];
    __syncthreads();
    size_t i = ((size_t)blockIdx.x * 256 + threadIdx.x) * 4;
    int c0 = (int)(i & 255);
    float4 v = *(const float4*)(y + i);
    v.x = fmaxf(fmaf(v.x, scs[c0 + 0], shs[c0 + 0]), 0.f);
    v.y = fmaxf(fmaf(v.y, scs[c0 + 1], shs[c0 + 1]), 0.f);
    v.z = fmaxf(fmaf(v.z, scs[c0 + 2], shs[c0 + 2]), 0.f);
    v.w = fmaxf(fmaf(v.w, scs[c0 + 3], shs[c0 + 3]), 0.f);
    *(float4*)(y + i) = v;
}

// ---------------------------------------------------------------------------
extern "C" void kernel_launch(void* const* d_in, const int* in_sizes, int n_in,
                              void* d_out, int out_size, void* d_ws, size_t ws_size,
                              hipStream_t stream) {
    const float* xyz1 = (const float*)d_in[0];
    const float* xyz2 = (const float*)d_in[1];
    const float* p1   = (const float*)d_in[2];
    const float* p2   = (const float*)d_in[3];
    const float* W1   = (const float*)d_in[4];
    // d_in[5] = b1  (cancels in batch-norm)
    const float* g1   = (const float*)d_in[6];
    const float* be1  = (const float*)d_in[7];
    const float* W2   = (const float*)d_in[8];
    // d_in[9] = b2  (cancels in batch-norm)
    const float* g2   = (const float*)d_in[10];
    const float* be2  = (const float*)d_in[11];
    float* out = (float*)d_out;

    // workspace layout (16B aligned).  KNN scratch overlays y1b (consumed by
    // interp_gather before GEMM1 writes y1b).  GEMM1 stats partials in d_out
    // (dead until GEMM2); GEMM2 partials in xb (dead after GEMM1).
    char* ws = (char*)d_ws;
    __bf16* xb     = (__bf16*)(ws);                    // 65536*384*2 = 50331648
    __bf16* y1b    = (__bf16*)(ws + 50331648);         // 65536*256*2 = 33554432
    float4* vals4  = (float4*)(ws + 50331648);         // 8*65536*16 = 8388608
    int4*   ci4    = (int4*)  (ws + 58720256);         // 8*65536*16 = 8388608
    float4* v4     = (float4*)(ws + 67108864);         // 65536*16   = 1048576
    float4* w4     = (float4*)(ws + 68157440);         // 65536*16   = 1048576
    __bf16* wb1    = (__bf16*)(ws + 83886080);         // 256*384*2
    __bf16* wb2    = (__bf16*)(ws + 84082688);         // 256*256*2
    float*  sc1    = (float*) (ws + 84213760);
    float*  sh1    = sc1 + 256;
    float*  sc2    = sc1 + 512;
    float*  sh2    = sc1 + 768;

    float* partS1 = (float*)d_out;            // 1024*128*4 = 512 KB
    float* partQ1 = partS1 + 131072;          // (d_out is 64 MB)
    float* partS2 = (float*)ws;               // xb region, dead during GEMM2
    float* partQ2 = partS2 + 131072;

    f2bf2<<<640, 256, 0, stream>>>(W1, H_OUT * CIN, W2, H_OUT * H_OUT, wb1, wb2);

    knn_vals<<<B_SZ * 32 * NCH, 256, 0, stream>>>(xyz1, xyz2, vals4);
    knn_merge<<<R_TOT / 256, 256, 0, stream>>>(vals4, xyz1, v4, w4);
    knn_recover<<<B_SZ * 32 * NCH, 256, 0, stream>>>(xyz1, xyz2, v4, ci4);
    interp_gather<<<R_TOT / QPB, 256, 0, stream>>>(p1, p2, ci4, w4, xb);

    gemm_bt<CIN, true><<<1024, 256, 0, stream>>>(xb, wb1, (void*)y1b, partS1, partQ1);
    bn_finalize<<<256, 256, 0, stream>>>(partS1, partQ1, g1, be1, sc1, sh1);
    apply_bf16<<<8192, 256, 0, stream>>>(y1b, sc1, sh1);

    gemm_bt<H_OUT, false><<<1024, 256, 0, stream>>>(y1b, wb2, (void*)out, partS2, partQ2);
    bn_finalize<<<256, 256, 0, stream>>>(partS2, partQ2, g2, be2, sc2, sh2);
    apply_f32<<<16384, 256, 0, stream>>>(out, sc2, sh2);
}